// Round 2
// baseline (513.439 us; speedup 1.0000x reference)
//
#include <hip/hip_runtime.h>
#include <stdint.h>

#define NND 200000   // N nodes; D_IN = D_OUT = 256, B = 256

typedef unsigned short u16;
typedef __attribute__((ext_vector_type(4))) float f4;
typedef __attribute__((ext_vector_type(4))) int   i4;
typedef __attribute__((ext_vector_type(2))) unsigned int u2;
typedef __attribute__((ext_vector_type(8))) short s8;   // 8 bf16 - MFMA A/B frag
typedef __attribute__((ext_vector_type(4))) float acc4; // MFMA C/D frag

__device__ __forceinline__ short f2bf(float f) {
    union { float f; uint32_t u; } v; v.f = f;
    uint32_t r = v.u + 0x7FFFu + ((v.u >> 16) & 1u);   // RNE
    return (short)(r >> 16);
}
__device__ __forceinline__ uint32_t pack2bf(float a, float b) {
    uint32_t ua = __float_as_uint(a), ub = __float_as_uint(b);
    ua = ua + 0x7FFFu + ((ua >> 16) & 1u);
    ub = ub + 0x7FFFu + ((ub >> 16) & 1u);
    return (ua >> 16) | (ub & 0xFFFF0000u);
}
__device__ __forceinline__ void gld16(const void* g, void* l) {
    __builtin_amdgcn_global_load_lds(
        (const __attribute__((address_space(1))) void*)g,
        (__attribute__((address_space(3))) void*)l, 16, 0, 0);
}
// barrier that does NOT drain vmcnt: LDS consistency only (T4). Keeps global
// loads (reg prefetch / gld16) in flight across the chunk boundary.
__device__ __forceinline__ void bar_lgkm() {
    asm volatile("s_waitcnt lgkmcnt(0)" ::: "memory");
    __builtin_amdgcn_s_barrier();
    asm volatile("" ::: "memory");
}

// ---------------- prep: W fp32 -> bf16 ----------------
__global__ __launch_bounds__(256) void k_prep(const float* __restrict__ Wt,
                                              const float* __restrict__ Wg,
                                              u16* __restrict__ wtb,
                                              u16* __restrict__ wgb) {
    int i = blockIdx.x * 256 + threadIdx.x;   // 256 blocks -> 65536 exactly
    wtb[i] = (u16)f2bf(Wt[i]);
    wgb[i] = (u16)f2bf(Wg[i]);
}

// ---------------- pass 1: h_t[d][n] = (nodes@Wt.T+bt)*sigmoid(nodes@Wg.T+bg) ----------------
// W-resident streaming, lgkm-only barriers, 2 blocks/CU.
// 500 blocks x 1024 threads (16 waves). Wave w owns d-slice w*16..w*16+15; W in regs.
// Nodes streamed in 32-row chunks through dbuf LDS; ONE lgkm-only barrier per chunk so the
// 2-ahead register prefetch genuinely stays in flight across chunk boundaries.
// 250 blocks x 13 + 250 x 12 chunks = 6250 x 32 = 200000 exactly.
__global__ __launch_bounds__(1024, 4) void k_h(const float* __restrict__ nodes,
                                               const u16* __restrict__ wtb,
                                               const u16* __restrict__ wgb,
                                               const float* __restrict__ btp,
                                               const float* __restrict__ bgp,
                                               u16* __restrict__ h_t) {
    // A dbuf: 2 x 16384 (32 rows x 256 k bf16, k-granule-major, xor-swizzled)
    // H dbuf: 2 x 18432 (256 d x 72B rows: 64B data + 8B pad -> conflict-free transpose)
    __shared__ __align__(16) char smem[69632];
    char* A0 = smem;
    char* A1 = smem + 16384;
    char* H0 = smem + 32768;
    char* H1 = smem + 51200;

    const int tid  = threadIdx.x;
    const int lane = tid & 63, wave = tid >> 6;
    const int quad = lane >> 4, l16 = lane & 15;
    const int dgl  = wave * 16 + l16;          // this lane's output-d (B-frag col)

    // ---- W fragments -> registers (once; wtb/wgb L2/L3-hot, 128KB total) ----
    s8 wT[8], wG[8];
    {
        const u16* wtp = wtb + dgl * 256 + quad * 8;
        const u16* wgp = wgb + dgl * 256 + quad * 8;
#pragma unroll
        for (int ks = 0; ks < 8; ++ks) {
            wT[ks] = *(const s8*)(wtp + ks * 32);
            wG[ks] = *(const s8*)(wgp + ks * 32);
        }
    }
    const float btv = btp[dgl], bgv = bgp[dgl];

    const int bid = blockIdx.x;
    const int NC  = (bid < 250) ? 13 : 12;
    const int c0  = (bid < 250) ? bid * 13 : 3250 + (bid - 250) * 12;

    const int arow = tid >> 5, akq = tid & 31; // A load: 32 thr/row -> contiguous 1KB/row
    const int awbyte = akq * 512 + (((arow & 24) | ((arow ^ akq) & 7)) << 4); // swizzled granule
    const int sd = tid >> 2, sc = tid & 3;     // H store: 4 thr/d-row, 16B each

    // ---- prologue: chunk c0 -> A0; prefetch chunk c0+1 into regs ----
    f4 ar0, ar1;
    {
        const f4* p = (const f4*)(nodes + (size_t)(c0 * 32 + arow) * 256 + akq * 8);
        ar0 = p[0]; ar1 = p[1];
        i4 aw;
        aw.x = (int)pack2bf(ar0.x, ar0.y); aw.y = (int)pack2bf(ar0.z, ar0.w);
        aw.z = (int)pack2bf(ar1.x, ar1.y); aw.w = (int)pack2bf(ar1.z, ar1.w);
        *(i4*)(A0 + awbyte) = aw;
        const f4* q = (const f4*)(nodes + (size_t)((c0 + 1) * 32 + arow) * 256 + akq * 8);
        ar0 = q[0]; ar1 = q[1];
    }
    bar_lgkm();

    char *Ard = A0, *Awr = A1, *Hwr = H0, *Hrd = H1;

    for (int c = 0; c < NC; ++c) {
        // ---- MFMA: 32 rows x 16 d x K=256, both matrices (32 MFMA/wave) ----
        acc4 at0 = (acc4)0.0f, at1 = (acc4)0.0f, ag0 = (acc4)0.0f, ag1 = (acc4)0.0f;
#pragma unroll
        for (int ks = 0; ks < 8; ++ks) {
            const int kq = ks * 4 + quad;
            const int ab = kq * 512 + (((l16 & 8) | ((l16 ^ kq) & 7)) << 4);
            s8 af0 = *(const s8*)(Ard + ab);         // rows  0..15
            s8 af1 = *(const s8*)(Ard + ab + 256);   // rows 16..31 (same slot +256B)
            at0 = __builtin_amdgcn_mfma_f32_16x16x32_bf16(af0, wT[ks], at0, 0, 0, 0);
            ag0 = __builtin_amdgcn_mfma_f32_16x16x32_bf16(af0, wG[ks], ag0, 0, 0, 0);
            at1 = __builtin_amdgcn_mfma_f32_16x16x32_bf16(af1, wT[ks], at1, 0, 0, 0);
            ag1 = __builtin_amdgcn_mfma_f32_16x16x32_bf16(af1, wG[ks], ag1, 0, 0, 0);
        }
        // ---- stage chunk c+1 (in regs; compiler inserts exact vmcnt) -> other A buf ----
        if (c < NC - 1) {
            i4 aw;
            aw.x = (int)pack2bf(ar0.x, ar0.y); aw.y = (int)pack2bf(ar0.z, ar0.w);
            aw.z = (int)pack2bf(ar1.x, ar1.y); aw.w = (int)pack2bf(ar1.z, ar1.w);
            *(i4*)(Awr + awbyte) = aw;
        }
        // ---- issue global loads for chunk c+2 (stay in flight across barrier now) ----
        if (c < NC - 2) {
            const f4* p = (const f4*)(nodes + (size_t)((c0 + c + 2) * 32 + arow) * 256 + akq * 8);
            ar0 = p[0]; ar1 = p[1];
        }
        // ---- epilogue: h = (data+bt)*sigmoid(gate+bg) -> bf16 -> Hwr (transpose tile) ----
#pragma unroll
        for (int rt = 0; rt < 2; ++rt) {
            const acc4 t = rt ? at1 : at0;
            const acc4 g = rt ? ag1 : ag0;
            float h0 = (t[0] + btv) / (1.0f + __expf(-(g[0] + bgv)));
            float h1 = (t[1] + btv) / (1.0f + __expf(-(g[1] + bgv)));
            float h2 = (t[2] + btv) / (1.0f + __expf(-(g[2] + bgv)));
            float h3 = (t[3] + btv) / (1.0f + __expf(-(g[3] + bgv)));
            u2 p; p.x = pack2bf(h0, h1); p.y = pack2bf(h2, h3);
            *(u2*)(Hwr + dgl * 72 + rt * 32 + quad * 8) = p;
        }
        // ---- coalesced store of PREVIOUS chunk's h tile (other H buffer) ----
        if (c > 0) {
            f4 v = *(const f4*)(Hrd + sd * 72 + sc * 16);
            *(f4*)(h_t + (size_t)sd * NND + (size_t)(c0 + c - 1) * 32 + sc * 8) = v;
        }
        bar_lgkm();
        char* tp = Ard; Ard = Awr; Awr = tp;
        tp = Hwr; Hwr = Hrd; Hrd = tp;
    }
    // ---- final store: chunk c0+NC-1 ----
    {
        f4 v = *(const f4*)(Hrd + sd * 72 + sc * 16);
        *(f4*)(h_t + (size_t)sd * NND + (size_t)(c0 + NC - 1) * 32 + sc * 8) = v;
    }
}

// ---------------- pass 2: res = mask @ h_t^T, split-K ----------------
// 256 blocks x 1024 threads (16 waves, 4x4 wave grid). Block = FULL 256b x 256d tile,
// so h_t is read exactly once (was twice). Per iter: K=64 nodes. Ms/Hs double-buffered,
// ONE lgkm-only barrier per iter; H staged via gld16 with COUNTED vmcnt(6)
// (2 gld16 + 4 mask loads stay in flight across the barrier); masks prefetched
// a full iter ahead in regs. 3125 chunks: first 53 blocks take 13, rest 12.
__global__ __launch_bounds__(1024, 4) void k_res(const int* __restrict__ masks,
                                                 const u16* __restrict__ h_t,
                                                 float* __restrict__ outp) {
    __shared__ __align__(16) char smem[131072];
    char* Ms0 = smem;            // 2 x 32768: 256 b x 128B bf16, xor-swizzled (reg-written)
    char* Hs0 = smem + 65536;    // 2 x 32768: 256 d x 128B bf16, swizzled-src gld16 dest

    const int tid  = threadIdx.x;
    const int lane = tid & 63, wave = tid >> 6;
    const int quad = lane >> 4, l16 = lane & 15;
    const int bh = wave & 3, dq = wave >> 2;   // 4x4 wave grid: 64b x 64d per wave

    const int bid = blockIdx.x;
    const int R   = 12 + (bid < 53 ? 1 : 0);
    const int it0 = bid * 12 + min(bid, 53);

    acc4 acc[4][4];
#pragma unroll
    for (int rt = 0; rt < 4; ++rt)
#pragma unroll
        for (int dt = 0; dt < 4; ++dt) acc[rt][dt] = (acc4)0.0f;

    const int mr = tid >> 2, seg = tid & 3;    // mask load: 4 thr/b-row, 16 ints each
    const size_t mrow = (size_t)mr * NND;

    // ---- prologue: masks(0) -> regs; issue gld16 H(0) -> Hs[0] ----
    i4 mp[4];
    {
        const int nb = it0 * 64;
        const i4* p = (const i4*)(masks + mrow + nb + seg * 16);
        mp[0] = p[0]; mp[1] = p[1]; mp[2] = p[2]; mp[3] = p[3];
#pragma unroll
        for (int i = 0; i < 2; ++i) {
            int g = i * 1024 + tid;
            int dr = g >> 3, c = g & 7;
            gld16(h_t + (size_t)dr * NND + nb + ((c ^ (dr & 7)) << 3), Hs0 + g * 16);
        }
    }

    int cur = 0;
    for (int it = 0; it < R; ++it) {
        const int nb = (it0 + it) * 64;
        // 1. convert prefetched mask regs -> bf16 -> Ms[cur] (2 x ds_write_b128)
        {
            uint32_t w0 = (((uint32_t)(-mp[0].x)) & 0x3F80u) | ((((uint32_t)(-mp[0].y)) & 0x3F80u) << 16);
            uint32_t w1 = (((uint32_t)(-mp[0].z)) & 0x3F80u) | ((((uint32_t)(-mp[0].w)) & 0x3F80u) << 16);
            uint32_t w2 = (((uint32_t)(-mp[1].x)) & 0x3F80u) | ((((uint32_t)(-mp[1].y)) & 0x3F80u) << 16);
            uint32_t w3 = (((uint32_t)(-mp[1].z)) & 0x3F80u) | ((((uint32_t)(-mp[1].w)) & 0x3F80u) << 16);
            uint32_t w4 = (((uint32_t)(-mp[2].x)) & 0x3F80u) | ((((uint32_t)(-mp[2].y)) & 0x3F80u) << 16);
            uint32_t w5 = (((uint32_t)(-mp[2].z)) & 0x3F80u) | ((((uint32_t)(-mp[2].w)) & 0x3F80u) << 16);
            uint32_t w6 = (((uint32_t)(-mp[3].x)) & 0x3F80u) | ((((uint32_t)(-mp[3].y)) & 0x3F80u) << 16);
            uint32_t w7 = (((uint32_t)(-mp[3].z)) & 0x3F80u) | ((((uint32_t)(-mp[3].w)) & 0x3F80u) << 16);
            i4 a, b;
            a.x = (int)w0; a.y = (int)w1; a.z = (int)w2; a.w = (int)w3;
            b.x = (int)w4; b.y = (int)w5; b.z = (int)w6; b.w = (int)w7;
            char* base = Ms0 + cur * 32768 + mr * 128;
            const int g0 = seg * 2;
            *(i4*)(base + (((g0    ) ^ (mr & 7)) << 4)) = a;
            *(i4*)(base + (((g0 + 1) ^ (mr & 7)) << 4)) = b;
        }
        // 2. prefetch next iter's masks -> regs (in flight through MFMA phase)
        if (it + 1 < R) {
            const i4* p = (const i4*)(masks + mrow + (nb + 64) + seg * 16);
            mp[0] = p[0]; mp[1] = p[1]; mp[2] = p[2]; mp[3] = p[3];
        }
        // 3. lgkm-only barrier: Ms[cur] visible; everyone done reading Hs[cur^1]
        bar_lgkm();
        // 4. issue gld16 H(it+1) -> Hs[cur^1]; 5. counted wait for H(it)
        if (it + 1 < R) {
#pragma unroll
            for (int i = 0; i < 2; ++i) {
                int g = i * 1024 + tid;
                int dr = g >> 3, c = g & 7;
                gld16(h_t + (size_t)dr * NND + (nb + 64) + ((c ^ (dr & 7)) << 3),
                      Hs0 + (cur ^ 1) * 32768 + g * 16);
            }
            // outstanding: [H(it) x2 oldest | mask(it+1) x4 | H(it+1) x2] -> keep 6 newest
            asm volatile("s_waitcnt vmcnt(6)" ::: "memory");
        } else {
            asm volatile("s_waitcnt vmcnt(0)" ::: "memory");
        }
        __builtin_amdgcn_sched_barrier(0);
        // 6. MFMA: 256b x 256d x K=64 per block; 32 MFMA/wave
        const char* Mr = Ms0 + cur * 32768;
        const char* Hr = Hs0 + cur * 32768;
#pragma unroll
        for (int ks = 0; ks < 2; ++ks) {
            const int q = (ks << 2) | quad;
            s8 af[4];
#pragma unroll
            for (int rt = 0; rt < 4; ++rt) {
                int r = bh * 64 + rt * 16 + l16;
                af[rt] = *(const s8*)(Mr + r * 128 + ((q ^ (r & 7)) << 4));
            }
#pragma unroll
            for (int dt = 0; dt < 4; ++dt) {
                int dl = dq * 64 + dt * 16 + l16;
                s8 bf_ = *(const s8*)(Hr + dl * 128 + ((q ^ (dl & 7)) << 4));
#pragma unroll
                for (int rt = 0; rt < 4; ++rt)
                    acc[rt][dt] = __builtin_amdgcn_mfma_f32_16x16x32_bf16(af[rt], bf_, acc[rt][dt], 0, 0, 0);
            }
        }
        cur ^= 1;
    }
#pragma unroll
    for (int rt = 0; rt < 4; ++rt)
#pragma unroll
        for (int dt = 0; dt < 4; ++dt) {
            int b = bh * 64 + rt * 16 + quad * 4;
            int d = dq * 64 + dt * 16 + l16;
#pragma unroll
            for (int r = 0; r < 4; ++r)
                atomicAdd(outp + (size_t)(b + r) * 256 + d, acc[rt][dt][r]);
        }
}

extern "C" void kernel_launch(void* const* d_in, const int* in_sizes, int n_in,
                              void* d_out, int out_size, void* d_ws, size_t ws_size,
                              hipStream_t stream) {
    const float* nodes = (const float*)d_in[0];
    const int*   masks = (const int*)d_in[1];
    const float* Wt    = (const float*)d_in[2];
    const float* bt    = (const float*)d_in[3];
    const float* Wg    = (const float*)d_in[4];
    const float* bg    = (const float*)d_in[5];
    float* outp = (float*)d_out;

    // ws layout: h_t bf16 [256][200000] = 102,400,000 B; then Wt/Wg bf16 (131072 B)
    u16* h_t = (u16*)d_ws;
    u16* wtb = (u16*)((char*)d_ws + (size_t)102400000);
    u16* wgb = wtb + 65536;

    hipMemsetAsync(d_out, 0, (size_t)out_size * sizeof(float), stream);
    k_prep<<<dim3(256), dim3(256), 0, stream>>>(Wt, Wg, wtb, wgb);
    k_h<<<dim3(500), dim3(1024), 0, stream>>>(nodes, wtb, wgb, bt, bg, h_t);
    k_res<<<dim3(256), dim3(1024), 0, stream>>>(masks, h_t, outp);
}